// Round 1
// baseline (655.334 us; speedup 1.0000x reference)
//
#include <hip/hip_runtime.h>
#include <math.h>

// SparseMOELayer: N=65536 tokens, D=128, E=16 experts, top-3 routing.
// Outputs concat: logits[N*D] | importance_loss[1] | comb[N*E]
#define NTOK 65536
#define DD   128
#define NE   16
#define NK   3
#define TPB  64                    // tokens per block (k_gate / k_expert)
#define NBLK (NTOK / TPB)          // 1024

#define OUT_LOSS ((size_t)NTOK * DD)
#define OUT_COMB ((size_t)NTOK * DD + 1)

__device__ __forceinline__ double softplus_d(double z) {
    return fmax(z, 0.0) + log1p(exp(-fabs(z)));
}

// ---------------------------------------------------------------------------
// K1: gating. 64 tokens/block, thread = (tl = tid>>4 token-lane, e = tid&15).
// fp64 accumulation so our gate ordering matches the (f64) numpy reference:
// top-k is discontinuous, fp32 dot error (~3e-7) risks rank-3/4 flips.
// ---------------------------------------------------------------------------
__global__ __launch_bounds__(256) void k_gate(
    const float* __restrict__ x, const float* __restrict__ noise,
    const float* __restrict__ Wg, const float* __restrict__ bg,
    const float* __restrict__ Wn, const float* __restrict__ bn,
    float* __restrict__ out, int* __restrict__ pe, float* __restrict__ pw,
    float* __restrict__ imp_block)
{
    __shared__ float  WgT[NE][DD + 4];   // transposed, +4 pad: conflict-free b128
    __shared__ float  WnT[NE][DD + 4];
    __shared__ float  xs[TPB][DD + 4];
    __shared__ double gate_s[TPB][NE + 1];
    __shared__ float  tk_w[TPB][NK];
    __shared__ int    tk_e[TPB][NK];
    __shared__ float  impS[NE];

    const int tid = threadIdx.x;
    const int n0  = blockIdx.x * TPB;
    const int e   = tid & 15;
    const int tl  = tid >> 4;

    if (tid < NE) impS[tid] = 0.0f;
    for (int i = tid; i < DD * NE; i += 256) {        // transpose-load Wg/Wn
        int d = i >> 4, ee = i & 15;
        WgT[ee][d] = Wg[i];
        WnT[ee][d] = Wn[i];
    }
    for (int i = tid; i < TPB * DD; i += 256) {       // stage x tile
        int t = i >> 7, d = i & 127;
        xs[t][d] = x[(size_t)(n0 + t) * DD + d];
    }
    __syncthreads();

    const double bge = (double)bg[e], bne = (double)bn[e];
    for (int g = 0; g < 4; g++) {
        int t = g * 16 + tl;
        const float4* xp  = (const float4*)&xs[t][0];
        const float4* wgp = (const float4*)&WgT[e][0];
        const float4* wnp = (const float4*)&WnT[e][0];
        double ga = 0.0, na = 0.0;
        #pragma unroll
        for (int q = 0; q < DD / 4; q++) {
            float4 xv = xp[q], wg = wgp[q], wn = wnp[q];
            ga += (double)xv.x * wg.x + (double)xv.y * wg.y
                + (double)xv.z * wg.z + (double)xv.w * wg.w;
            na += (double)xv.x * wn.x + (double)xv.y * wn.y
                + (double)xv.z * wn.z + (double)xv.w * wn.w;
        }
        double nz = (double)noise[(size_t)(n0 + t) * NE + e];
        gate_s[t][e] = ga + bge + nz * softplus_d(na + bne);
    }
    __syncthreads();

    if (tid < TPB) {                                   // top-3 per token
        int t = tid;
        double v[NK]; int ix[NK];
        unsigned taken = 0;
        for (int k = 0; k < NK; k++) {
            double best = -INFINITY; int bi = 0;
            for (int j = 0; j < NE; j++) {
                if (!((taken >> j) & 1u)) {
                    double gv = gate_s[t][j];
                    if (gv > best) { best = gv; bi = j; }  // strict >: lowest idx on tie
                }
            }
            taken |= 1u << bi;
            v[k] = best; ix[k] = bi;
        }
        double e1 = exp(v[1] - v[0]);
        double e2 = exp(v[2] - v[0]);
        double inv = 1.0 / (1.0 + e1 + e2);
        float w0 = (float)inv, w1 = (float)(e1 * inv), w2 = (float)(e2 * inv);
        tk_e[t][0] = ix[0]; tk_e[t][1] = ix[1]; tk_e[t][2] = ix[2];
        tk_w[t][0] = w0;    tk_w[t][1] = w1;    tk_w[t][2] = w2;
        size_t pb = (size_t)(n0 + t) * NK;
        pe[pb + 0] = ix[0]; pe[pb + 1] = ix[1]; pe[pb + 2] = ix[2];
        pw[pb + 0] = w0;    pw[pb + 1] = w1;    pw[pb + 2] = w2;
    }
    __syncthreads();

    for (int g = 0; g < 4; g++) {                      // comb + importance partials
        int t = g * 16 + tl;
        float c = 0.f;
        if (tk_e[t][0] == e) c = tk_w[t][0];
        if (tk_e[t][1] == e) c = tk_w[t][1];
        if (tk_e[t][2] == e) c = tk_w[t][2];
        out[OUT_COMB + (size_t)(n0 + t) * NE + e] = c;
        if (c != 0.f) atomicAdd(&impS[e], c);
    }
    __syncthreads();
    if (tid < NE) imp_block[blockIdx.x * NE + tid] = impS[tid];
}

// ---------------------------------------------------------------------------
// K2: importance loss = (std(imp, ddof=1)/mean)^2, from 1024x16 partials.
// ---------------------------------------------------------------------------
__global__ __launch_bounds__(256) void k_loss(
    const float* __restrict__ imp_block, float* __restrict__ out)
{
    __shared__ float red[256];
    __shared__ float impv[NE];
    int tid = threadIdx.x;
    int e = tid & 15, s = tid >> 4;
    float sum = 0.f;
    for (int b = s; b < NBLK; b += 16) sum += imp_block[b * NE + e];
    red[tid] = sum;
    __syncthreads();
    if (tid < NE) {
        float t = 0.f;
        for (int q = 0; q < 16; q++) t += red[q * 16 + tid];
        impv[tid] = t;
    }
    __syncthreads();
    if (tid == 0) {
        double mean = 0.0;
        for (int i = 0; i < NE; i++) mean += (double)impv[i];
        mean /= NE;
        double var = 0.0;
        for (int i = 0; i < NE; i++) {
            double d = (double)impv[i] - mean; var += d * d;
        }
        var /= (NE - 1);                    // ddof=1
        out[OUT_LOSS] = (float)(var / (mean * mean));
    }
}

// ---------------------------------------------------------------------------
// K3: expert compute, token-major tiles of 64. Per-tile per-expert gathered
// token lists in LDS; accumulate into LDS yacc (tile owns its tokens
// exclusively -> no global atomics); one coalesced logits write.
// Thread = (fq = tid&31 -> f=4*fq..+3, tg = tid>>5 -> 2 slots of 16-chunk).
// ---------------------------------------------------------------------------
__global__ __launch_bounds__(256) void k_expert(
    const float* __restrict__ x, const float* __restrict__ We,
    const float* __restrict__ be,
    const int* __restrict__ pe, const float* __restrict__ pw,
    float* __restrict__ out)
{
    __shared__ float yacc[TPB][DD];            // 32 KB accumulator tile
    __shared__ int   lcnt[NE];
    __shared__ unsigned char lslot[NE][TPB];   // entry = t | (k<<6)
    __shared__ float pwS[TPB][NK];

    const int tid = threadIdx.x;
    const int n0  = blockIdx.x * TPB;

    if (tid < NE) lcnt[tid] = 0;
    __syncthreads();
    if (tid < TPB) {                            // build per-expert lists
        size_t pb = (size_t)(n0 + tid) * NK;
        for (int k = 0; k < NK; k++) {
            int   ee = pe[pb + k];
            float w  = pw[pb + k];
            pwS[tid][k] = w;
            int r = atomicAdd(&lcnt[ee], 1);
            lslot[ee][r] = (unsigned char)(tid | (k << 6));
        }
    }
    __syncthreads();
    for (int idx = tid; idx < TPB * DD; idx += 256) {   // init yacc with bias
        int t = idx >> 7, f = idx & 127;
        size_t pb = (size_t)(n0 + t) * NK;
        float sv = 0.f;
        for (int k = 0; k < NK; k++)
            sv += pwS[t][k] * be[(size_t)pe[pb + k] * DD + f];
        yacc[t][f] = sv;
    }
    __syncthreads();

    const int fq = tid & 31;
    const int tg = tid >> 5;
    for (int e = 0; e < NE; e++) {
        const int m = lcnt[e];
        const float* Wp = We + (size_t)e * DD * DD + 4 * fq;
        for (int c0 = 0; c0 < m; c0 += 16) {
            int sA = c0 + 2 * tg, sB = sA + 1;
            int tA = 0, tB = 0; float wA = 0.f, wB = 0.f;
            if (sA < m) { int ent = lslot[e][sA]; tA = ent & 63; wA = pwS[tA][ent >> 6]; }
            if (sB < m) { int ent = lslot[e][sB]; tB = ent & 63; wB = pwS[tB][ent >> 6]; }
            const float* xA = x + (size_t)(n0 + tA) * DD;
            const float* xB = x + (size_t)(n0 + tB) * DD;
            float a0 = 0.f, a1 = 0.f, a2 = 0.f, a3 = 0.f;
            float b0 = 0.f, b1 = 0.f, b2 = 0.f, b3 = 0.f;
            #pragma unroll 4
            for (int d = 0; d < DD; d++) {
                float4 wr = *(const float4*)(Wp + (size_t)d * DD);
                float xa = xA[d], xb = xB[d];
                a0 = fmaf(xa, wr.x, a0); a1 = fmaf(xa, wr.y, a1);
                a2 = fmaf(xa, wr.z, a2); a3 = fmaf(xa, wr.w, a3);
                b0 = fmaf(xb, wr.x, b0); b1 = fmaf(xb, wr.y, b1);
                b2 = fmaf(xb, wr.z, b2); b3 = fmaf(xb, wr.w, b3);
            }
            // distinct tokens within an expert list -> no RMW race inside epoch
            if (sA < m) {
                float* yp = &yacc[tA][4 * fq];
                yp[0] += wA * a0; yp[1] += wA * a1; yp[2] += wA * a2; yp[3] += wA * a3;
            }
            if (sB < m) {
                float* yp = &yacc[tB][4 * fq];
                yp[0] += wB * b0; yp[1] += wB * b1; yp[2] += wB * b2; yp[3] += wB * b3;
            }
        }
        __syncthreads();   // tokens recur across experts -> barrier per expert
    }

    const float* ys = &yacc[0][0];
    float* op = out + (size_t)n0 * DD;
    for (int idx = tid; idx < TPB * DD; idx += 256)
        op[idx] = ys[idx];                      // coalesced final write
}

// ---------------------------------------------------------------------------
extern "C" void kernel_launch(void* const* d_in, const int* in_sizes, int n_in,
                              void* d_out, int out_size, void* d_ws, size_t ws_size,
                              hipStream_t stream)
{
    (void)in_sizes; (void)n_in; (void)out_size; (void)ws_size;
    const float* x     = (const float*)d_in[0];
    const float* noise = (const float*)d_in[1];
    const float* Wg    = (const float*)d_in[2];
    const float* bg    = (const float*)d_in[3];
    const float* Wn    = (const float*)d_in[4];
    const float* bn    = (const float*)d_in[5];
    const float* We    = (const float*)d_in[6];
    const float* be    = (const float*)d_in[7];
    float* out = (float*)d_out;

    char*  ws        = (char*)d_ws;
    int*   pe        = (int*)ws;                    // 196608 * 4 B
    float* pw        = (float*)(ws + 786432);       // 196608 * 4 B
    float* imp_block = (float*)(ws + 1572864);      // 16384  * 4 B  (~1.6 MB total)

    hipLaunchKernelGGL(k_gate, dim3(NBLK), dim3(256), 0, stream,
                       x, noise, Wg, bg, Wn, bn, out, pe, pw, imp_block);
    hipLaunchKernelGGL(k_loss, dim3(1), dim3(256), 0, stream, imp_block, out);
    hipLaunchKernelGGL(k_expert, dim3(NBLK), dim3(256), 0, stream,
                       x, We, be, pe, pw, out);
}

// Round 2
// 321.223 us; speedup vs baseline: 2.0401x; 2.0401x over previous
//
#include <hip/hip_runtime.h>
#include <math.h>

// SparseMOELayer: N=65536 tokens, D=128, E=16 experts, top-3 routing.
// Outputs concat: logits[N*D] | importance_loss[1] | comb[N*E]
#define NTOK 65536
#define DD   128
#define NE   16
#define NK   3
#define TPB  64                    // tokens per block (k_gate / k_expert)
#define NBLK (NTOK / TPB)          // 1024

#define OUT_LOSS ((size_t)NTOK * DD)
#define OUT_COMB ((size_t)NTOK * DD + 1)

typedef __bf16 bf16x8 __attribute__((ext_vector_type(8)));
typedef float  f32x4  __attribute__((ext_vector_type(4)));

__device__ __forceinline__ double softplus_d(double z) {
    return fmax(z, 0.0) + log1p(exp(-fabs(z)));
}

// ---------------------------------------------------------------------------
// K0: We[e][d][f] fp32 -> WeT[e][f][d] bf16 (B-operand-friendly layout).
// 16 blocks, one expert each. Tiny (~8 MB read), perf-irrelevant.
// ---------------------------------------------------------------------------
__global__ __launch_bounds__(256) void k_prep(
    const float* __restrict__ We, __bf16* __restrict__ WeT)
{
    __shared__ __bf16 S[DD][DD + 8];
    const int tid = threadIdx.x;
    const int e = blockIdx.x;
    const size_t base = (size_t)e * DD * DD;
    for (int idx = tid; idx < DD * DD; idx += 256) {
        int d = idx >> 7, f = idx & 127;
        S[d][f] = (__bf16)We[base + idx];              // coalesced read
    }
    __syncthreads();
    for (int idx = tid; idx < DD * DD; idx += 256) {
        int f = idx >> 7, d = idx & 127;
        WeT[base + idx] = S[d][f];                     // coalesced write
    }
}

// ---------------------------------------------------------------------------
// K1: gating (unchanged from R1 — correct; will optimize with evidence).
// fp64 accumulation so gate ordering matches the numpy reference: top-k is
// discontinuous, fp32 dot error risks rank-3/4 flips.
// ---------------------------------------------------------------------------
__global__ __launch_bounds__(256) void k_gate(
    const float* __restrict__ x, const float* __restrict__ noise,
    const float* __restrict__ Wg, const float* __restrict__ bg,
    const float* __restrict__ Wn, const float* __restrict__ bn,
    float* __restrict__ out, int* __restrict__ pe, float* __restrict__ pw,
    float* __restrict__ imp_block)
{
    __shared__ float  WgT[NE][DD + 4];
    __shared__ float  WnT[NE][DD + 4];
    __shared__ float  xs[TPB][DD + 4];
    __shared__ double gate_s[TPB][NE + 1];
    __shared__ float  tk_w[TPB][NK];
    __shared__ int    tk_e[TPB][NK];
    __shared__ float  impS[NE];

    const int tid = threadIdx.x;
    const int n0  = blockIdx.x * TPB;
    const int e   = tid & 15;
    const int tl  = tid >> 4;

    if (tid < NE) impS[tid] = 0.0f;
    for (int i = tid; i < DD * NE; i += 256) {
        int d = i >> 4, ee = i & 15;
        WgT[ee][d] = Wg[i];
        WnT[ee][d] = Wn[i];
    }
    for (int i = tid; i < TPB * DD; i += 256) {
        int t = i >> 7, d = i & 127;
        xs[t][d] = x[(size_t)(n0 + t) * DD + d];
    }
    __syncthreads();

    const double bge = (double)bg[e], bne = (double)bn[e];
    for (int g = 0; g < 4; g++) {
        int t = g * 16 + tl;
        const float4* xp  = (const float4*)&xs[t][0];
        const float4* wgp = (const float4*)&WgT[e][0];
        const float4* wnp = (const float4*)&WnT[e][0];
        double ga = 0.0, na = 0.0;
        #pragma unroll
        for (int q = 0; q < DD / 4; q++) {
            float4 xv = xp[q], wg = wgp[q], wn = wnp[q];
            ga += (double)xv.x * wg.x + (double)xv.y * wg.y
                + (double)xv.z * wg.z + (double)xv.w * wg.w;
            na += (double)xv.x * wn.x + (double)xv.y * wn.y
                + (double)xv.z * wn.z + (double)xv.w * wn.w;
        }
        double nz = (double)noise[(size_t)(n0 + t) * NE + e];
        gate_s[t][e] = ga + bge + nz * softplus_d(na + bne);
    }
    __syncthreads();

    if (tid < TPB) {                                   // top-3 per token
        int t = tid;
        double v[NK]; int ix[NK];
        unsigned taken = 0;
        for (int k = 0; k < NK; k++) {
            double best = -INFINITY; int bi = 0;
            for (int j = 0; j < NE; j++) {
                if (!((taken >> j) & 1u)) {
                    double gv = gate_s[t][j];
                    if (gv > best) { best = gv; bi = j; }
                }
            }
            taken |= 1u << bi;
            v[k] = best; ix[k] = bi;
        }
        double e1 = exp(v[1] - v[0]);
        double e2 = exp(v[2] - v[0]);
        double inv = 1.0 / (1.0 + e1 + e2);
        float w0 = (float)inv, w1 = (float)(e1 * inv), w2 = (float)(e2 * inv);
        tk_e[t][0] = ix[0]; tk_e[t][1] = ix[1]; tk_e[t][2] = ix[2];
        tk_w[t][0] = w0;    tk_w[t][1] = w1;    tk_w[t][2] = w2;
        size_t pb = (size_t)(n0 + t) * NK;
        pe[pb + 0] = ix[0]; pe[pb + 1] = ix[1]; pe[pb + 2] = ix[2];
        pw[pb + 0] = w0;    pw[pb + 1] = w1;    pw[pb + 2] = w2;
    }
    __syncthreads();

    for (int g = 0; g < 4; g++) {                      // comb + importance
        int t = g * 16 + tl;
        float c = 0.f;
        if (tk_e[t][0] == e) c = tk_w[t][0];
        if (tk_e[t][1] == e) c = tk_w[t][1];
        if (tk_e[t][2] == e) c = tk_w[t][2];
        out[OUT_COMB + (size_t)(n0 + t) * NE + e] = c;
        if (c != 0.f) atomicAdd(&impS[e], c);
    }
    __syncthreads();
    if (tid < NE) imp_block[blockIdx.x * NE + tid] = impS[tid];
}

// ---------------------------------------------------------------------------
// K2: importance loss = (std(imp, ddof=1)/mean)^2.
// ---------------------------------------------------------------------------
__global__ __launch_bounds__(256) void k_loss(
    const float* __restrict__ imp_block, float* __restrict__ out)
{
    __shared__ float red[256];
    __shared__ float impv[NE];
    int tid = threadIdx.x;
    int e = tid & 15, s = tid >> 4;
    float sum = 0.f;
    for (int b = s; b < NBLK; b += 16) sum += imp_block[b * NE + e];
    red[tid] = sum;
    __syncthreads();
    if (tid < NE) {
        float t = 0.f;
        for (int q = 0; q < 16; q++) t += red[q * 16 + tid];
        impv[tid] = t;
    }
    __syncthreads();
    if (tid == 0) {
        double mean = 0.0;
        for (int i = 0; i < NE; i++) mean += (double)impv[i];
        mean /= NE;
        double var = 0.0;
        for (int i = 0; i < NE; i++) {
            double d = (double)impv[i] - mean; var += d * d;
        }
        var /= (NE - 1);
        out[OUT_LOSS] = (float)(var / (mean * mean));
    }
}

// ---------------------------------------------------------------------------
// K3: expert compute via MFMA. 64-token tile per block; per-expert gathered
// 16-token m-tiles; mfma_f32_16x16x32_bf16 with A from LDS (ds_read_b128),
// B-frags from global WeT (L1/L2-hot, 512 KB total). Each of the 4 waves
// owns a 32-column slice of yacc -> no cross-wave races, NO barrier in the
// expert loop. fp32 accumulate in LDS yacc; single coalesced write.
//
// MFMA 16x16x32 layouts (m89-verified):
//   A: lane l holds A[m=l&15][k=(l>>4)*8+j], j=0..7   (16B contiguous in k)
//   B: lane l holds B[k=(l>>4)*8+j][n=l&15]           (16B contiguous in d via WeT)
//   D: col=l&15, row=(l>>4)*4+reg
// ---------------------------------------------------------------------------
__global__ __launch_bounds__(256) void k_expert(
    const float* __restrict__ x, const __bf16* __restrict__ WeT,
    const float* __restrict__ be,
    const int* __restrict__ pe, const float* __restrict__ pw,
    float* __restrict__ out)
{
    __shared__ __bf16 xsb[TPB][DD + 8];        // 17.4 KB, bf16 x tile
    __shared__ float  yacc[TPB][DD + 4];       // 33.8 KB fp32 accumulator
    __shared__ int    lcnt[NE];
    __shared__ unsigned char lslot[NE][TPB];   // entry = t | (k<<6)
    __shared__ float  pwS[TPB][NK];
    __shared__ int    peS[TPB][NK];

    const int tid  = threadIdx.x;
    const int n0   = blockIdx.x * TPB;
    const int lane = tid & 63;
    const int wid  = tid >> 6;                 // wave id 0..3 -> cols wid*32..+31
    const int l15  = lane & 15;
    const int quad = lane >> 4;

    if (tid < NE) lcnt[tid] = 0;
    __syncthreads();
    if (tid < TPB) {                            // build per-expert lists
        size_t pb = (size_t)(n0 + tid) * NK;
        for (int k = 0; k < NK; k++) {
            int   ee = pe[pb + k];
            float w  = pw[pb + k];
            pwS[tid][k] = w; peS[tid][k] = ee;
            int r = atomicAdd(&lcnt[ee], 1);
            lslot[ee][r] = (unsigned char)(tid | (k << 6));
        }
    }
    // stage x tile as bf16 (coalesced fp32 read)
    for (int idx = tid; idx < TPB * DD; idx += 256) {
        int t = idx >> 7, d = idx & 127;
        xsb[t][d] = (__bf16)x[(size_t)(n0 + t) * DD + d];
    }
    __syncthreads();
    // init yacc with routed bias: sum_k w_k * be[e_k][f]
    for (int idx = tid; idx < TPB * DD; idx += 256) {
        int t = idx >> 7, f = idx & 127;
        float sv = 0.f;
        #pragma unroll
        for (int k = 0; k < NK; k++)
            sv += pwS[t][k] * be[(size_t)peS[t][k] * DD + f];
        yacc[t][f] = sv;
    }
    __syncthreads();

    const int nA = wid * 32;                   // this wave's two 16-col tiles
    const int nB = nA + 16;
    for (int e = 0; e < NE; e++) {
        const int m = lcnt[e];
        if (m == 0) continue;
        // B fragments for this expert (reused across m-tiles)
        bf16x8 Bf[2][4];
        const __bf16* bbase = WeT + (size_t)e * DD * DD;
        #pragma unroll
        for (int t2 = 0; t2 < 2; t2++) {
            int n = nA + 16 * t2 + l15;
            #pragma unroll
            for (int s = 0; s < 4; s++)
                Bf[t2][s] = *(const bf16x8*)(bbase + (size_t)n * DD + 32 * s + quad * 8);
        }
        for (int c0 = 0; c0 < m; c0 += 16) {
            int slot = c0 + l15;
            int tok  = 0;
            if (slot < m) tok = lslot[e][slot] & 63;
            f32x4 acc0 = {0.f, 0.f, 0.f, 0.f};
            f32x4 acc1 = {0.f, 0.f, 0.f, 0.f};
            #pragma unroll
            for (int s = 0; s < 4; s++) {
                bf16x8 Af = *(const bf16x8*)&xsb[tok][32 * s + quad * 8];
                acc0 = __builtin_amdgcn_mfma_f32_16x16x32_bf16(Af, Bf[0][s], acc0, 0, 0, 0);
                acc1 = __builtin_amdgcn_mfma_f32_16x16x32_bf16(Af, Bf[1][s], acc1, 0, 0, 0);
            }
            // epilogue: row m = quad*4 + r; lanes hit distinct (token,col)
            #pragma unroll
            for (int r = 0; r < 4; r++) {
                int slot2 = c0 + quad * 4 + r;
                if (slot2 < m) {
                    int ent = lslot[e][slot2];
                    int tk  = ent & 63;
                    float w = pwS[tk][ent >> 6];
                    yacc[tk][nA + l15] += w * acc0[r];
                    yacc[tk][nB + l15] += w * acc1[r];
                }
            }
        }
    }
    __syncthreads();

    float* op = out + (size_t)n0 * DD;
    for (int idx = tid; idx < TPB * DD; idx += 256) {
        int t = idx >> 7, f = idx & 127;
        op[idx] = yacc[t][f];                   // coalesced final write
    }
}

// ---------------------------------------------------------------------------
extern "C" void kernel_launch(void* const* d_in, const int* in_sizes, int n_in,
                              void* d_out, int out_size, void* d_ws, size_t ws_size,
                              hipStream_t stream)
{
    (void)in_sizes; (void)n_in; (void)out_size; (void)ws_size;
    const float* x     = (const float*)d_in[0];
    const float* noise = (const float*)d_in[1];
    const float* Wg    = (const float*)d_in[2];
    const float* bg    = (const float*)d_in[3];
    const float* Wn    = (const float*)d_in[4];
    const float* bn    = (const float*)d_in[5];
    const float* We    = (const float*)d_in[6];
    const float* be    = (const float*)d_in[7];
    float* out = (float*)d_out;

    char*   ws        = (char*)d_ws;
    int*    pe        = (int*)ws;                    // 196608*4 = 768 KB
    float*  pw        = (float*)(ws + 786432);       // 768 KB
    float*  imp_block = (float*)(ws + 1572864);      // 64 KB
    __bf16* WeT       = (__bf16*)(ws + 1638400);     // 512 KB (16B aligned)

    hipLaunchKernelGGL(k_prep, dim3(NE), dim3(256), 0, stream, We, WeT);
    hipLaunchKernelGGL(k_gate, dim3(NBLK), dim3(256), 0, stream,
                       x, noise, Wg, bg, Wn, bn, out, pe, pw, imp_block);
    hipLaunchKernelGGL(k_loss, dim3(1), dim3(256), 0, stream, imp_block, out);
    hipLaunchKernelGGL(k_expert, dim3(NBLK), dim3(256), 0, stream,
                       x, WeT, be, pe, pw, out);
}

// Round 3
// 222.159 us; speedup vs baseline: 2.9498x; 1.4459x over previous
//
#include <hip/hip_runtime.h>
#include <math.h>

// SparseMOELayer: N=65536 tokens, D=128, E=16 experts, top-3 routing.
// Outputs concat: logits[N*D] | importance_loss[1] | comb[N*E]
#define NTOK 65536
#define DD   128
#define NE   16
#define NK   3
#define TPB  64                    // tokens per block (k_gate / k_expert)
#define NBLK (NTOK / TPB)          // 1024

#define OUT_LOSS ((size_t)NTOK * DD)
#define OUT_COMB ((size_t)NTOK * DD + 1)

typedef __bf16 bf16x8 __attribute__((ext_vector_type(8)));
typedef float  f32x4  __attribute__((ext_vector_type(4)));

__device__ __forceinline__ double softplus_d(double z) {
    return fmax(z, 0.0) + log1p(exp(-fabs(z)));
}

// ---------------------------------------------------------------------------
// K0: We[e][d][f] fp32 -> WeT[e][f][d] bf16 (B-operand-friendly layout).
// ---------------------------------------------------------------------------
__global__ __launch_bounds__(256) void k_prep(
    const float* __restrict__ We, __bf16* __restrict__ WeT)
{
    __shared__ __bf16 S[DD][DD + 8];
    const int tid = threadIdx.x;
    const int e = blockIdx.x;
    const size_t base = (size_t)e * DD * DD;
    for (int idx = tid; idx < DD * DD; idx += 256) {
        int d = idx >> 7, f = idx & 127;
        S[d][f] = (__bf16)We[base + idx];              // coalesced read
    }
    __syncthreads();
    for (int idx = tid; idx < DD * DD; idx += 256) {
        int f = idx >> 7, d = idx & 127;
        WeT[base + idx] = S[d][f];                     // coalesced write
    }
}

// ---------------------------------------------------------------------------
// K1: gating, phase-split to control register pressure.
//  - fp64 accumulation (our gate ≈ exact; top-k flips vs numpy's fp32 ref
//    only where numpy's own error crosses a gap — irreducible).
//  - No x LDS tile: 16 lanes/token read identical float4 -> broadcast + L1.
//  - Phase 1 (dot, ILP-4 fp64 accs) | barrier | Phase 2 (softplus) |
//    barrier | Phase 3 (top-k) | Phase 4 (comb+importance).
//  - __launch_bounds__(256,4): cap 128 VGPR -> 4 waves/SIMD; LDS ~35 KB
//    -> 4 blocks/CU.
// ---------------------------------------------------------------------------
__global__ __launch_bounds__(256, 4) void k_gate(
    const float* __restrict__ x, const float* __restrict__ noise,
    const float* __restrict__ Wg, const float* __restrict__ bg,
    const float* __restrict__ Wn, const float* __restrict__ bn,
    float* __restrict__ out, int* __restrict__ pe, float* __restrict__ pw,
    float* __restrict__ imp_block)
{
    __shared__ float  WgT[NE][DD + 4];   // transposed gate weights
    __shared__ float  WnT[NE][DD + 4];
    __shared__ double gaS[TPB][NE + 1];  // gate dot -> final gate value
    __shared__ double naS[TPB][NE + 1];  // noise-gate dot
    __shared__ float  tk_w[TPB][NK];
    __shared__ int    tk_e[TPB][NK];
    __shared__ float  impS[NE];

    const int tid = threadIdx.x;
    const int n0  = blockIdx.x * TPB;
    const int e   = tid & 15;
    const int tl  = tid >> 4;

    if (tid < NE) impS[tid] = 0.0f;
    for (int i = tid; i < DD * NE; i += 256) {        // transpose-load Wg/Wn
        int d = i >> 4, ee = i & 15;
        WgT[ee][d] = Wg[i];
        WnT[ee][d] = Wn[i];
    }
    __syncthreads();

    // ---- Phase 1: fp64 dots, 8 independent accumulator chains ----
    const float4* wgp = (const float4*)&WgT[e][0];
    const float4* wnp = (const float4*)&WnT[e][0];
    for (int g = 0; g < 4; g++) {
        int t = g * 16 + tl;
        const float4* xp = (const float4*)(x + (size_t)(n0 + t) * DD);
        double g0 = 0, g1 = 0, g2 = 0, g3 = 0;
        double h0 = 0, h1 = 0, h2 = 0, h3 = 0;
        #pragma unroll 4
        for (int q = 0; q < DD / 4; q++) {
            float4 xv = xp[q], wg = wgp[q], wn = wnp[q];
            g0 += (double)xv.x * wg.x; g1 += (double)xv.y * wg.y;
            g2 += (double)xv.z * wg.z; g3 += (double)xv.w * wg.w;
            h0 += (double)xv.x * wn.x; h1 += (double)xv.y * wn.y;
            h2 += (double)xv.z * wn.z; h3 += (double)xv.w * wn.w;
        }
        gaS[t][e] = (g0 + g1) + (g2 + g3);
        naS[t][e] = (h0 + h1) + (h2 + h3);
    }
    __syncthreads();

    // ---- Phase 2: gate = ga + bg + noise * softplus(na + bn) ----
    {
        const double bge = (double)bg[e], bne = (double)bn[e];
        for (int g = 0; g < 4; g++) {
            int t = g * 16 + tl;
            double nz = (double)noise[(size_t)(n0 + t) * NE + e];
            gaS[t][e] = gaS[t][e] + bge + nz * softplus_d(naS[t][e] + bne);
        }
    }
    __syncthreads();

    // ---- Phase 3: top-3 per token (64 threads) ----
    if (tid < TPB) {
        int t = tid;
        double v[NK]; int ix[NK];
        unsigned taken = 0;
        for (int k = 0; k < NK; k++) {
            double best = -INFINITY; int bi = 0;
            for (int j = 0; j < NE; j++) {
                if (!((taken >> j) & 1u)) {
                    double gv = gaS[t][j];
                    if (gv > best) { best = gv; bi = j; }  // strict >: low idx on tie
                }
            }
            taken |= 1u << bi;
            v[k] = best; ix[k] = bi;
        }
        double e1 = exp(v[1] - v[0]);
        double e2 = exp(v[2] - v[0]);
        double inv = 1.0 / (1.0 + e1 + e2);
        float w0 = (float)inv, w1 = (float)(e1 * inv), w2 = (float)(e2 * inv);
        tk_e[t][0] = ix[0]; tk_e[t][1] = ix[1]; tk_e[t][2] = ix[2];
        tk_w[t][0] = w0;    tk_w[t][1] = w1;    tk_w[t][2] = w2;
        size_t pb = (size_t)(n0 + t) * NK;
        pe[pb + 0] = ix[0]; pe[pb + 1] = ix[1]; pe[pb + 2] = ix[2];
        pw[pb + 0] = w0;    pw[pb + 1] = w1;    pw[pb + 2] = w2;
    }
    __syncthreads();

    // ---- Phase 4: comb scatter + importance partials ----
    for (int g = 0; g < 4; g++) {
        int t = g * 16 + tl;
        float c = 0.f;
        if (tk_e[t][0] == e) c = tk_w[t][0];
        if (tk_e[t][1] == e) c = tk_w[t][1];
        if (tk_e[t][2] == e) c = tk_w[t][2];
        out[OUT_COMB + (size_t)(n0 + t) * NE + e] = c;
        if (c != 0.f) atomicAdd(&impS[e], c);
    }
    __syncthreads();
    if (tid < NE) imp_block[blockIdx.x * NE + tid] = impS[tid];
}

// ---------------------------------------------------------------------------
// K2: importance loss = (std(imp, ddof=1)/mean)^2.
// ---------------------------------------------------------------------------
__global__ __launch_bounds__(256) void k_loss(
    const float* __restrict__ imp_block, float* __restrict__ out)
{
    __shared__ float red[256];
    __shared__ float impv[NE];
    int tid = threadIdx.x;
    int e = tid & 15, s = tid >> 4;
    float sum = 0.f;
    for (int b = s; b < NBLK; b += 16) sum += imp_block[b * NE + e];
    red[tid] = sum;
    __syncthreads();
    if (tid < NE) {
        float t = 0.f;
        for (int q = 0; q < 16; q++) t += red[q * 16 + tid];
        impv[tid] = t;
    }
    __syncthreads();
    if (tid == 0) {
        double mean = 0.0;
        for (int i = 0; i < NE; i++) mean += (double)impv[i];
        mean /= NE;
        double var = 0.0;
        for (int i = 0; i < NE; i++) {
            double d = (double)impv[i] - mean; var += d * d;
        }
        var /= (NE - 1);
        out[OUT_LOSS] = (float)(var / (mean * mean));
    }
}

// ---------------------------------------------------------------------------
// K3: expert compute via MFMA (unchanged from R2; counters next round).
// ---------------------------------------------------------------------------
__global__ __launch_bounds__(256) void k_expert(
    const float* __restrict__ x, const __bf16* __restrict__ WeT,
    const float* __restrict__ be,
    const int* __restrict__ pe, const float* __restrict__ pw,
    float* __restrict__ out)
{
    __shared__ __bf16 xsb[TPB][DD + 8];        // 17.4 KB, bf16 x tile
    __shared__ float  yacc[TPB][DD + 4];       // 33.8 KB fp32 accumulator
    __shared__ int    lcnt[NE];
    __shared__ unsigned char lslot[NE][TPB];   // entry = t | (k<<6)
    __shared__ float  pwS[TPB][NK];
    __shared__ int    peS[TPB][NK];

    const int tid  = threadIdx.x;
    const int n0   = blockIdx.x * TPB;
    const int lane = tid & 63;
    const int wid  = tid >> 6;                 // wave id 0..3 -> cols wid*32..+31
    const int l15  = lane & 15;
    const int quad = lane >> 4;

    if (tid < NE) lcnt[tid] = 0;
    __syncthreads();
    if (tid < TPB) {                            // build per-expert lists
        size_t pb = (size_t)(n0 + tid) * NK;
        for (int k = 0; k < NK; k++) {
            int   ee = pe[pb + k];
            float w  = pw[pb + k];
            pwS[tid][k] = w; peS[tid][k] = ee;
            int r = atomicAdd(&lcnt[ee], 1);
            lslot[ee][r] = (unsigned char)(tid | (k << 6));
        }
    }
    for (int idx = tid; idx < TPB * DD; idx += 256) {
        int t = idx >> 7, d = idx & 127;
        xsb[t][d] = (__bf16)x[(size_t)(n0 + t) * DD + d];
    }
    __syncthreads();
    for (int idx = tid; idx < TPB * DD; idx += 256) {   // init yacc with bias
        int t = idx >> 7, f = idx & 127;
        float sv = 0.f;
        #pragma unroll
        for (int k = 0; k < NK; k++)
            sv += pwS[t][k] * be[(size_t)peS[t][k] * DD + f];
        yacc[t][f] = sv;
    }
    __syncthreads();

    const int nA = wid * 32;                   // this wave's two 16-col tiles
    const int nB = nA + 16;
    for (int e = 0; e < NE; e++) {
        const int m = lcnt[e];
        if (m == 0) continue;
        bf16x8 Bf[2][4];
        const __bf16* bbase = WeT + (size_t)e * DD * DD;
        #pragma unroll
        for (int t2 = 0; t2 < 2; t2++) {
            int n = nA + 16 * t2 + l15;
            #pragma unroll
            for (int s = 0; s < 4; s++)
                Bf[t2][s] = *(const bf16x8*)(bbase + (size_t)n * DD + 32 * s + quad * 8);
        }
        for (int c0 = 0; c0 < m; c0 += 16) {
            int slot = c0 + l15;
            int tok  = 0;
            if (slot < m) tok = lslot[e][slot] & 63;
            f32x4 acc0 = {0.f, 0.f, 0.f, 0.f};
            f32x4 acc1 = {0.f, 0.f, 0.f, 0.f};
            #pragma unroll
            for (int s = 0; s < 4; s++) {
                bf16x8 Af = *(const bf16x8*)&xsb[tok][32 * s + quad * 8];
                acc0 = __builtin_amdgcn_mfma_f32_16x16x32_bf16(Af, Bf[0][s], acc0, 0, 0, 0);
                acc1 = __builtin_amdgcn_mfma_f32_16x16x32_bf16(Af, Bf[1][s], acc1, 0, 0, 0);
            }
            #pragma unroll
            for (int r = 0; r < 4; r++) {
                int slot2 = c0 + quad * 4 + r;
                if (slot2 < m) {
                    int ent = lslot[e][slot2];
                    int tk  = ent & 63;
                    float w = pwS[tk][ent >> 6];
                    yacc[tk][nA + l15] += w * acc0[r];
                    yacc[tk][nB + l15] += w * acc1[r];
                }
            }
        }
    }
    __syncthreads();

    float* op = out + (size_t)n0 * DD;
    for (int idx = tid; idx < TPB * DD; idx += 256) {
        int t = idx >> 7, f = idx & 127;
        op[idx] = yacc[t][f];                   // coalesced final write
    }
}

// ---------------------------------------------------------------------------
extern "C" void kernel_launch(void* const* d_in, const int* in_sizes, int n_in,
                              void* d_out, int out_size, void* d_ws, size_t ws_size,
                              hipStream_t stream)
{
    (void)in_sizes; (void)n_in; (void)out_size; (void)ws_size;
    const float* x     = (const float*)d_in[0];
    const float* noise = (const float*)d_in[1];
    const float* Wg    = (const float*)d_in[2];
    const float* bg    = (const float*)d_in[3];
    const float* Wn    = (const float*)d_in[4];
    const float* bn    = (const float*)d_in[5];
    const float* We    = (const float*)d_in[6];
    const float* be    = (const float*)d_in[7];
    float* out = (float*)d_out;

    char*   ws        = (char*)d_ws;
    int*    pe        = (int*)ws;                    // 196608*4 = 768 KB
    float*  pw        = (float*)(ws + 786432);       // 768 KB
    float*  imp_block = (float*)(ws + 1572864);      // 64 KB
    __bf16* WeT       = (__bf16*)(ws + 1638400);     // 512 KB (16B aligned)

    hipLaunchKernelGGL(k_prep, dim3(NE), dim3(256), 0, stream, We, WeT);
    hipLaunchKernelGGL(k_gate, dim3(NBLK), dim3(256), 0, stream,
                       x, noise, Wg, bg, Wn, bn, out, pe, pw, imp_block);
    hipLaunchKernelGGL(k_loss, dim3(1), dim3(256), 0, stream, imp_block, out);
    hipLaunchKernelGGL(k_expert, dim3(NBLK), dim3(256), 0, stream,
                       x, WeT, be, pe, pw, out);
}